// Round 4
// baseline (10754.712 us; speedup 1.0000x reference)
//
#include <hip/hip_runtime.h>
#include <math.h>

// Problem constants
#define B 128
#define T 256
#define D 512
#define H 1024
#define KTOT 1536   // D + H
#define N4 4096     // 4*H

typedef short short8 __attribute__((ext_vector_type(8)));
typedef float f32x16 __attribute__((ext_vector_type(16)));

__device__ __forceinline__ unsigned short f2bf(float f) {
    unsigned int u = __builtin_bit_cast(unsigned int, f);
    unsigned int r = (u + 0x7fffu + ((u >> 16) & 1u)) >> 16;  // RNE
    return (unsigned short)r;
}
__device__ __forceinline__ float bf2f(unsigned short s) {
    unsigned int u = ((unsigned int)s) << 16;
    return __builtin_bit_cast(float, u);
}
__device__ __forceinline__ float sigm(float x) { return 1.f / (1.f + __expf(-x)); }
__device__ __forceinline__ float tanh_fast(float x) {
    return 1.f - 2.f / (1.f + __expf(2.f * x));
}

// x fp32 [B][T][D] -> xb bf16 [T][B][D]
__global__ __launch_bounds__(256) void convert_x(
    const float* __restrict__ x, unsigned short* __restrict__ xb)
{
    int bid = blockIdx.x;          // t*B + b
    int t = bid >> 7;
    int b = bid & 127;
    int d = threadIdx.x * 2;
    const float2 v = *(const float2*)&x[((size_t)b * T + t) * D + d];
    unsigned int packed = (unsigned int)f2bf(v.x) | ((unsigned int)f2bf(v.y) << 16);
    *(unsigned int*)&xb[((size_t)t * B + b) * D + d] = packed;
}

// Wk fp32 [KTOT][4H] -> Wp bf16 [4096][KTOT], permuted: pcol = hc*4 + g
// (n = g*H + hc  ->  pcol = ((n & 1023) << 2) | (n >> 10))
__global__ __launch_bounds__(256) void convert_W(
    const float* __restrict__ Wk, unsigned short* __restrict__ Wp)
{
    __shared__ float tile[32][33];
    int nb = blockIdx.x;   // 0..127
    int kb = blockIdx.y;   // 0..47
    int tx = threadIdx.x & 31;
    int ty = threadIdx.x >> 5;   // 0..7
    #pragma unroll
    for (int i = 0; i < 4; ++i) {
        int k = kb * 32 + ty + i * 8;
        tile[ty + i * 8][tx] = Wk[(size_t)k * N4 + nb * 32 + tx];
    }
    __syncthreads();
    #pragma unroll
    for (int i = 0; i < 4; ++i) {
        int n = nb * 32 + ty + i * 8;
        int pcol = ((n & 1023) << 2) | (n >> 10);
        Wp[(size_t)pcol * KTOT + kb * 32 + tx] = f2bf(tile[tx][ty + i * 8]);
    }
}

// Persistent LSTM: 256 blocks x 256 threads, 1 block/CU, W in registers.
// Block (rg = bi>>6, cg = bi&63): rows [32rg,+32), h-cols [16cg,+16)
// (= permuted z-cols [64cg,+64)). Waves: ch = col-half, kh = K-half.
// Wave: 32 rows x 32 pcols x 768 K via 48 mfma_f32_32x32x16_bf16;
// B-frags live in 192 VGPRs for the whole kernel. c-state in registers.
__global__ __launch_bounds__(256, 1) void lstm_persist(
    const unsigned short* __restrict__ xb,   // [T][B][D] bf16
    const unsigned short* __restrict__ Wp,   // [4096][KTOT] bf16 permuted
    const float* __restrict__ bk,            // [4H]
    unsigned short* __restrict__ h0,         // [B][H] bf16 ping (h_{-1}=0; final h)
    unsigned short* __restrict__ h1,         // [B][H] bf16 pong
    unsigned int* __restrict__ arr)          // [4][256] arrive counters (zeroed)
{
    __shared__ float zbuf[2][64][36];   // [kh][pcol-local][row], padded

    const int tid  = threadIdx.x;
    const int bi   = blockIdx.x;
    const int rg   = bi >> 6;
    const int cg   = bi & 63;
    const int w    = tid >> 6;
    const int lane = tid & 63;
    const int ch   = w & 1;
    const int kh   = w >> 1;
    const int l31  = lane & 31;
    const int lhi  = lane >> 5;   // 0/1

    const int row = rg * 32 + l31;             // A row (m = lane&31)
    const int pc  = cg * 64 + ch * 32 + l31;   // B pcol (n = lane&31)

    // ---- load W fragments into registers (forever) ----
    // chunk c (0..47) -> global k16-chunk g = 2c + kh; frag k = g*16 + lhi*8 + j
    short8 wb[48];
    const unsigned short* wbase = Wp + (size_t)pc * KTOT + lhi * 8;
    #pragma unroll
    for (int c = 0; c < 48; ++c)
        wb[c] = *(const short8*)(wbase + (2 * c + kh) * 16);

    // ---- bias preload for this thread's two gate elements ----
    float bi_[2], bj_[2], bf_[2], bo_[2];
    #pragma unroll
    for (int u = 0; u < 2; ++u) {
        int e   = tid + u * 256;
        int hcl = e >> 5;                 // 0..15
        int hcg = cg * 16 + hcl;
        bi_[u] = bk[hcg];
        bj_[u] = bk[H + hcg];
        bf_[u] = bk[2 * H + hcg] + 1.0f;  // forget bias folded
        bo_[u] = bk[3 * H + hcg];
    }
    float cs0 = 0.f, cs1 = 0.f;   // cell state, persistent in registers

    unsigned int* const arrg = arr + rg * 256;
    const unsigned short* const hb0 = h0 + (size_t)row * H + lhi * 8 - 512;
    const unsigned short* const hb1 = h1 + (size_t)row * H + lhi * 8 - 512;

    for (int t = 0; t < T; ++t) {
        f32x16 accA = {0.f,0.f,0.f,0.f,0.f,0.f,0.f,0.f,
                       0.f,0.f,0.f,0.f,0.f,0.f,0.f,0.f};
        f32x16 accB = accA;

        // ---- x-part (chunks 0..15): no dependency on h, runs pre-sync ----
        const unsigned short* xr =
            xb + ((size_t)t * B + row) * D + lhi * 8;
        #pragma unroll
        for (int c = 0; c < 16; c += 2) {
            short8 a0 = *(const short8*)(xr + (2 * c + kh) * 16);
            short8 a1 = *(const short8*)(xr + (2 * (c + 1) + kh) * 16);
            accA = __builtin_amdgcn_mfma_f32_32x32x16_bf16(a0, wb[c], accA, 0, 0, 0);
            accB = __builtin_amdgcn_mfma_f32_32x32x16_bf16(a1, wb[c + 1], accB, 0, 0, 0);
        }

        // ---- wait for h_{t-1} from the 64 blocks of this row-group ----
        if (t > 0) {
            const unsigned int* ap = &arrg[t - 1];
            while (__hip_atomic_load(ap, __ATOMIC_RELAXED,
                                     __HIP_MEMORY_SCOPE_AGENT) < 64u)
                __builtin_amdgcn_s_sleep(1);
            __threadfence();   // acquire: invalidate caches so h is fresh
        }

        // ---- h-part (chunks 16..47) ----
        const unsigned short* hr = (t & 1) ? hb1 : hb0;
        #pragma unroll
        for (int c = 16; c < 48; c += 2) {
            short8 a0 = *(const short8*)(hr + (2 * c + kh) * 16);
            short8 a1 = *(const short8*)(hr + (2 * (c + 1) + kh) * 16);
            accA = __builtin_amdgcn_mfma_f32_32x32x16_bf16(a0, wb[c], accA, 0, 0, 0);
            accB = __builtin_amdgcn_mfma_f32_32x32x16_bf16(a1, wb[c + 1], accB, 0, 0, 0);
        }
        accA += accB;

        // ---- K-partials to LDS. C/D: col = lane&31, row = (reg&3)+8*(reg>>2)+4*lhi
        #pragma unroll
        for (int q = 0; q < 4; ++q) {
            float4 v = { accA[4 * q + 0], accA[4 * q + 1],
                         accA[4 * q + 2], accA[4 * q + 3] };
            *(float4*)&zbuf[kh][ch * 32 + l31][lhi * 4 + q * 8] = v;
        }
        __syncthreads();

        // ---- gates: 512 h-elems/block, 2 per thread ----
        unsigned short* hw = (t & 1) ? h0 : h1;
        #pragma unroll
        for (int u = 0; u < 2; ++u) {
            int e   = tid + u * 256;
            int r   = e & 31;
            int hcl = e >> 5;
            int pcb = hcl * 4;
            float zi = zbuf[0][pcb + 0][r] + zbuf[1][pcb + 0][r] + bi_[u];
            float zj = zbuf[0][pcb + 1][r] + zbuf[1][pcb + 1][r] + bj_[u];
            float zf = zbuf[0][pcb + 2][r] + zbuf[1][pcb + 2][r] + bf_[u];
            float zo = zbuf[0][pcb + 3][r] + zbuf[1][pcb + 3][r] + bo_[u];
            float& cc = u ? cs1 : cs0;
            float cn = cc * sigm(zf) + sigm(zi) * tanh_fast(zj);
            cc = cn;
            float hn = sigm(zo) * tanh_fast(cn);
            hw[(size_t)(rg * 32 + r) * H + cg * 16 + hcl] = f2bf(hn);
        }
        __syncthreads();   // all h-stores drained (vmcnt) before signaling

        if (tid == 0) {
            __threadfence();   // release: write back dirty L2 (cross-XCD)
            __hip_atomic_fetch_add(&arrg[t], 1u, __ATOMIC_RELEASE,
                                   __HIP_MEMORY_SCOPE_AGENT);
        }
    }
}

// out[128][1000] = h(bf16)[128][1024] @ w[1024][1000] + b
__global__ __launch_bounds__(256) void proj_kernel(
    const unsigned short* __restrict__ hb, const float* __restrict__ w,
    const float* __restrict__ bias, float* __restrict__ out)
{
    int cidx = blockIdx.x * 256 + threadIdx.x;  // 0..1023
    int bg   = blockIdx.y;                      // 0..7 -> 16 rows each
    bool valid = cidx < 1000;
    float acc[16];
    #pragma unroll
    for (int i = 0; i < 16; ++i) acc[i] = 0.f;

    for (int k = 0; k < H; k += 4) {
        float w0 = 0.f, w1 = 0.f, w2 = 0.f, w3 = 0.f;
        if (valid) {
            w0 = w[(size_t)(k + 0) * 1000 + cidx];
            w1 = w[(size_t)(k + 1) * 1000 + cidx];
            w2 = w[(size_t)(k + 2) * 1000 + cidx];
            w3 = w[(size_t)(k + 3) * 1000 + cidx];
        }
        #pragma unroll
        for (int i = 0; i < 16; ++i) {
            ushort4 hv = *(const ushort4*)&hb[(size_t)(bg * 16 + i) * H + k];
            acc[i] += bf2f(hv.x) * w0 + bf2f(hv.y) * w1
                    + bf2f(hv.z) * w2 + bf2f(hv.w) * w3;
        }
    }
    if (valid) {
        #pragma unroll
        for (int i = 0; i < 16; ++i)
            out[(size_t)(bg * 16 + i) * 1000 + cidx] = acc[i] + bias[cidx];
    }
}

extern "C" void kernel_launch(void* const* d_in, const int* in_sizes, int n_in,
                              void* d_out, int out_size, void* d_ws, size_t ws_size,
                              hipStream_t stream) {
    const float* x  = (const float*)d_in[0];  // [B,T,D]
    const float* Wk = (const float*)d_in[1];  // [D+H, 4H]
    const float* bk = (const float*)d_in[2];  // [4H]
    const float* w  = (const float*)d_in[3];  // [H, C]
    const float* b  = (const float*)d_in[4];  // [C]
    float* out = (float*)d_out;               // [B, C]

    char* p = (char*)d_ws;
    unsigned short* xb = (unsigned short*)p;  p += (size_t)B * T * D * 2;   // 33.55 MB
    unsigned short* Wp = (unsigned short*)p;  p += (size_t)N4 * KTOT * 2;   // 12.58 MB
    unsigned short* h0 = (unsigned short*)p;  p += (size_t)B * H * 2;
    unsigned short* h1 = (unsigned short*)p;  p += (size_t)B * H * 2;
    unsigned int*   ar = (unsigned int*)p;    p += 4 * 256 * 4;

    // ws re-poisoned 0xAA before every timed call — zero state + counters.
    hipMemsetAsync(h0, 0, (size_t)B * H * 2, stream);
    hipMemsetAsync(ar, 0, 4 * 256 * 4, stream);

    convert_x<<<dim3(T * B), dim3(256), 0, stream>>>(x, xb);
    convert_W<<<dim3(N4 / 32, KTOT / 32), dim3(256), 0, stream>>>(Wk, Wp);

    lstm_persist<<<dim3(256), dim3(256), 0, stream>>>(xb, Wp, bk, h0, h1, ar);

    // t=255 read h1, wrote h0 -> final hidden state in h0
    proj_kernel<<<dim3(4, 8), dim3(256), 0, stream>>>(h0, w, b, out);
}

// Round 5
// 2179.353 us; speedup vs baseline: 4.9348x; 4.9348x over previous
//
#include <hip/hip_runtime.h>
#include <math.h>

// Problem constants
#define B 128
#define T 256
#define D 512
#define H 1024
#define KTOT 1536   // D + H
#define N4 4096     // 4*H

typedef short short8 __attribute__((ext_vector_type(8)));
typedef float f32x16 __attribute__((ext_vector_type(16)));

__device__ __forceinline__ unsigned short f2bf(float f) {
    unsigned int u = __builtin_bit_cast(unsigned int, f);
    unsigned int r = (u + 0x7fffu + ((u >> 16) & 1u)) >> 16;  // RNE
    return (unsigned short)r;
}
__device__ __forceinline__ float bf2f(unsigned short s) {
    unsigned int u = ((unsigned int)s) << 16;
    return __builtin_bit_cast(float, u);
}
__device__ __forceinline__ float sigm(float x) { return 1.f / (1.f + __expf(-x)); }
__device__ __forceinline__ float tanh_fast(float x) {
    return 1.f - 2.f / (1.f + __expf(2.f * x));
}

// x fp32 [B][T][D] -> xb bf16 [T][B][D]
__global__ __launch_bounds__(256) void convert_x(
    const float* __restrict__ x, unsigned short* __restrict__ xb)
{
    int bid = blockIdx.x;          // t*B + b
    int t = bid >> 7;
    int b = bid & 127;
    int d = threadIdx.x * 2;
    const float2 v = *(const float2*)&x[((size_t)b * T + t) * D + d];
    unsigned int packed = (unsigned int)f2bf(v.x) | ((unsigned int)f2bf(v.y) << 16);
    *(unsigned int*)&xb[((size_t)t * B + b) * D + d] = packed;
}

// Wk fp32 [KTOT][4H] -> Wp bf16 [4096][KTOT], permuted: pcol = hc*4 + g
__global__ __launch_bounds__(256) void convert_W(
    const float* __restrict__ Wk, unsigned short* __restrict__ Wp)
{
    __shared__ float tile[32][33];
    int nb = blockIdx.x;   // 0..127
    int kb = blockIdx.y;   // 0..47
    int tx = threadIdx.x & 31;
    int ty = threadIdx.x >> 5;   // 0..7
    #pragma unroll
    for (int i = 0; i < 4; ++i) {
        int k = kb * 32 + ty + i * 8;
        tile[ty + i * 8][tx] = Wk[(size_t)k * N4 + nb * 32 + tx];
    }
    __syncthreads();
    #pragma unroll
    for (int i = 0; i < 4; ++i) {
        int n = nb * 32 + ty + i * 8;
        int pcol = ((n & 1023) << 2) | (n >> 10);
        Wp[(size_t)pcol * KTOT + kb * 32 + tx] = f2bf(tile[tx][ty + i * 8]);
    }
}

// Persistent LSTM. 256 blocks x 256 threads, 1 block/CU, W in registers.
// Cross-block h exchange entirely through agent-scope (LLC) atomics — no
// __threadfence / buffer_wbl2 / buffer_inv anywhere in the loop.
__global__ __launch_bounds__(256, 1) void lstm_persist(
    const unsigned short* __restrict__ xb,   // [T][B][D] bf16
    const unsigned short* __restrict__ Wp,   // [4096][KTOT] bf16 permuted
    const float* __restrict__ bk,            // [4H]
    unsigned short* __restrict__ h0,         // [B][H] bf16 ping (final h)
    unsigned short* __restrict__ h1,         // [B][H] bf16 pong
    unsigned int* __restrict__ arr)          // [4][256] arrive counters (zeroed)
{
    // LDS union: htile (64 KB, used for h-MFMA) overlaps zbuf+hbuf (used after)
    __shared__ __align__(16) char smem[65536];
    float (*zbuf)[64][36] = (float (*)[64][36])smem;                    // [2][64][36] = 18432 B
    unsigned short (*hbuf)[20] = (unsigned short (*)[20])(smem + 18432); // 32x20 ush = 1280 B

    const int tid  = threadIdx.x;
    const int bi   = blockIdx.x;
    const int rg   = bi >> 6;      // row-group: rows [32rg, +32)
    const int cg   = bi & 63;      // h-cols [16cg, +16) = pcols [64cg, +64)
    const int w    = tid >> 6;
    const int lane = tid & 63;
    const int ch   = w & 1;        // col-half
    const int kh   = w >> 1;       // K-half
    const int l31  = lane & 31;
    const int lhi  = lane >> 5;    // 0/1

    const int row = rg * 32 + l31;             // A row (m = lane&31)
    const int pc  = cg * 64 + ch * 32 + l31;   // B pcol (n = lane&31)

    // ---- W fragments into registers, forever ----
    // chunk c (0..47) -> k16-chunk g = 2c + kh; frag k = g*16 + lhi*8 + j
    short8 wb[48];
    const unsigned short* wbase = Wp + (size_t)pc * KTOT + lhi * 8;
    #pragma unroll
    for (int c = 0; c < 48; ++c)
        wb[c] = *(const short8*)(wbase + (2 * c + kh) * 16);

    // ---- bias preload for this thread's two gate elements ----
    float bi_[2], bj_[2], bf_[2], bo_[2];
    #pragma unroll
    for (int u = 0; u < 2; ++u) {
        int e   = tid + u * 256;
        int hcl = e >> 5;                 // 0..15
        int hcg = cg * 16 + hcl;
        bi_[u] = bk[hcg];
        bj_[u] = bk[H + hcg];
        bf_[u] = bk[2 * H + hcg] + 1.0f;  // forget bias folded
        bo_[u] = bk[3 * H + hcg];
    }
    float cs0 = 0.f, cs1 = 0.f;   // cell state, persistent in registers

    unsigned int* const arrg = arr + rg * 256;
    const unsigned int* const h0slab = (const unsigned int*)(h0 + (size_t)rg * 32 * H);
    const unsigned int* const h1slab = (const unsigned int*)(h1 + (size_t)rg * 32 * H);

    for (int t = 0; t < T; ++t) {
        f32x16 accA = {0.f,0.f,0.f,0.f,0.f,0.f,0.f,0.f,
                       0.f,0.f,0.f,0.f,0.f,0.f,0.f,0.f};
        f32x16 accB = accA;

        // ---- x-part (chunks 0..15): cached loads, no h dependency ----
        const unsigned short* xr = xb + ((size_t)t * B + row) * D + lhi * 8;
        #pragma unroll
        for (int c = 0; c < 16; c += 2) {
            short8 a0 = *(const short8*)(xr + (2 * c + kh) * 16);
            short8 a1 = *(const short8*)(xr + (2 * (c + 1) + kh) * 16);
            accA = __builtin_amdgcn_mfma_f32_32x32x16_bf16(a0, wb[c], accA, 0, 0, 0);
            accB = __builtin_amdgcn_mfma_f32_32x32x16_bf16(a1, wb[c + 1], accB, 0, 0, 0);
        }

        if (t > 0) {
            // ---- leader-only poll for h_{t-1} of this row-group ----
            if (tid == 0) {
                while (__hip_atomic_load(&arrg[t - 1], __ATOMIC_RELAXED,
                                         __HIP_MEMORY_SCOPE_AGENT) < 64u)
                    __builtin_amdgcn_s_sleep(2);
            }
            __syncthreads();
            asm volatile("" ::: "memory");

            // ---- stage h slab (32 rows x 1024 bf16 = 64 KB) into LDS ----
            // coalesced agent-scope loads (LLC), XOR-swizzled 16B groups
            const unsigned int* hsrc = (t & 1) ? h1slab : h0slab;
            #pragma unroll
            for (int ib = 0; ib < 4; ++ib) {
                unsigned int tmp[16];
                #pragma unroll
                for (int j = 0; j < 16; ++j)
                    tmp[j] = __hip_atomic_load(&hsrc[(ib * 16 + j) * 256 + tid],
                                               __ATOMIC_RELAXED,
                                               __HIP_MEMORY_SCOPE_AGENT);
                #pragma unroll
                for (int j = 0; j < 16; ++j) {
                    int K   = ib * 16 + j;
                    int r   = K >> 1;                    // LDS row 0..31
                    int cu  = ((K & 1) << 8) + tid;      // uint col 0..511
                    int grp = (cu >> 2) ^ (r & 7);       // 16B-group swizzle
                    *(unsigned int*)(smem + r * 2048 + grp * 16 + (cu & 3) * 4) = tmp[j];
                }
            }
            __syncthreads();

            // ---- h-part (chunks 16..47) from LDS ----
            #pragma unroll
            for (int c = 16; c < 48; c += 2) {
                int hc0 = (2 * c + kh) * 16 + lhi * 8 - 512;
                int hc1 = (2 * (c + 1) + kh) * 16 + lhi * 8 - 512;
                short8 a0 = *(const short8*)(smem + l31 * 2048 +
                                             (((hc0 >> 3) ^ (l31 & 7)) * 16));
                short8 a1 = *(const short8*)(smem + l31 * 2048 +
                                             (((hc1 >> 3) ^ (l31 & 7)) * 16));
                accA = __builtin_amdgcn_mfma_f32_32x32x16_bf16(a0, wb[c], accA, 0, 0, 0);
                accB = __builtin_amdgcn_mfma_f32_32x32x16_bf16(a1, wb[c + 1], accB, 0, 0, 0);
            }
            __syncthreads();   // htile dead before zbuf overwrites it
        }

        accA += accB;

        // ---- K-partials to LDS. C/D: col=lane&31, row=(reg&3)+8*(reg>>2)+4*lhi
        #pragma unroll
        for (int q = 0; q < 4; ++q) {
            float4 v = { accA[4 * q + 0], accA[4 * q + 1],
                         accA[4 * q + 2], accA[4 * q + 3] };
            *(float4*)&zbuf[kh][ch * 32 + l31][lhi * 4 + q * 8] = v;
        }
        __syncthreads();

        // ---- gates: 512 h-elems/block, 2 per thread; results to hbuf (LDS) ----
        #pragma unroll
        for (int u = 0; u < 2; ++u) {
            int e   = tid + u * 256;
            int r   = e & 31;
            int hcl = e >> 5;
            int pcb = hcl * 4;
            float zi = zbuf[0][pcb + 0][r] + zbuf[1][pcb + 0][r] + bi_[u];
            float zj = zbuf[0][pcb + 1][r] + zbuf[1][pcb + 1][r] + bj_[u];
            float zf = zbuf[0][pcb + 2][r] + zbuf[1][pcb + 2][r] + bf_[u];
            float zo = zbuf[0][pcb + 3][r] + zbuf[1][pcb + 3][r] + bo_[u];
            float& cc = u ? cs1 : cs0;
            float cn = cc * sigm(zf) + sigm(zi) * tanh_fast(zj);
            cc = cn;
            float hn = sigm(zo) * tanh_fast(cn);
            hbuf[r][hcl] = f2bf(hn);
        }
        __syncthreads();

        // ---- coalesced h-store: 256 uint agent-scope (LLC) stores ----
        {
            int r  = tid >> 3;
            int cp = tid & 7;
            unsigned int v = *(const unsigned int*)&hbuf[r][cp * 2];
            unsigned int* hdst = (unsigned int*)((t & 1) ? h0 : h1);
            __hip_atomic_store(&hdst[(size_t)(rg * 32 + r) * 512 + cg * 8 + cp], v,
                               __ATOMIC_RELAXED, __HIP_MEMORY_SCOPE_AGENT);
        }
        __syncthreads();   // drains vmcnt: all stores at LLC before signaling
        asm volatile("" ::: "memory");

        if (tid == 0)
            __hip_atomic_fetch_add(&arrg[t], 1u, __ATOMIC_RELAXED,
                                   __HIP_MEMORY_SCOPE_AGENT);
    }
}

// out[128][1000] = h(bf16)[128][1024] @ w[1024][1000] + b
__global__ __launch_bounds__(256) void proj_kernel(
    const unsigned short* __restrict__ hb, const float* __restrict__ w,
    const float* __restrict__ bias, float* __restrict__ out)
{
    int cidx = blockIdx.x * 256 + threadIdx.x;  // 0..1023
    int bg   = blockIdx.y;                      // 0..7 -> 16 rows each
    bool valid = cidx < 1000;
    float acc[16];
    #pragma unroll
    for (int i = 0; i < 16; ++i) acc[i] = 0.f;

    for (int k = 0; k < H; k += 4) {
        float w0 = 0.f, w1 = 0.f, w2 = 0.f, w3 = 0.f;
        if (valid) {
            w0 = w[(size_t)(k + 0) * 1000 + cidx];
            w1 = w[(size_t)(k + 1) * 1000 + cidx];
            w2 = w[(size_t)(k + 2) * 1000 + cidx];
            w3 = w[(size_t)(k + 3) * 1000 + cidx];
        }
        #pragma unroll
        for (int i = 0; i < 16; ++i) {
            ushort4 hv = *(const ushort4*)&hb[(size_t)(bg * 16 + i) * H + k];
            acc[i] += bf2f(hv.x) * w0 + bf2f(hv.y) * w1
                    + bf2f(hv.z) * w2 + bf2f(hv.w) * w3;
        }
    }
    if (valid) {
        #pragma unroll
        for (int i = 0; i < 16; ++i)
            out[(size_t)(bg * 16 + i) * 1000 + cidx] = acc[i] + bias[cidx];
    }
}

extern "C" void kernel_launch(void* const* d_in, const int* in_sizes, int n_in,
                              void* d_out, int out_size, void* d_ws, size_t ws_size,
                              hipStream_t stream) {
    const float* x  = (const float*)d_in[0];  // [B,T,D]
    const float* Wk = (const float*)d_in[1];  // [D+H, 4H]
    const float* bk = (const float*)d_in[2];  // [4H]
    const float* w  = (const float*)d_in[3];  // [H, C]
    const float* b  = (const float*)d_in[4];  // [C]
    float* out = (float*)d_out;               // [B, C]

    char* p = (char*)d_ws;
    unsigned short* xb = (unsigned short*)p;  p += (size_t)B * T * D * 2;   // 33.55 MB
    unsigned short* Wp = (unsigned short*)p;  p += (size_t)N4 * KTOT * 2;   // 12.58 MB
    unsigned short* h0 = (unsigned short*)p;  p += (size_t)B * H * 2;
    unsigned short* h1 = (unsigned short*)p;  p += (size_t)B * H * 2;
    unsigned int*   ar = (unsigned int*)p;    p += 4 * 256 * 4;

    // arr must start zeroed (ws re-poisoned 0xAA before every timed call).
    // h0/h1 need no init: t=0 skips the h-read entirely.
    hipMemsetAsync(ar, 0, 4 * 256 * 4, stream);

    convert_x<<<dim3(T * B), dim3(256), 0, stream>>>(x, xb);
    convert_W<<<dim3(N4 / 32, KTOT / 32), dim3(256), 0, stream>>>(Wk, Wp);

    lstm_persist<<<dim3(256), dim3(256), 0, stream>>>(xb, Wp, bk, h0, h1, ar);

    // t=255 (odd) wrote h0 -> final hidden state in h0
    proj_kernel<<<dim3(4, 8), dim3(256), 0, stream>>>(h0, w, b, out);
}